// Round 1
// baseline (40.934 us; speedup 1.0000x reference)
//
#include <hip/hip_runtime.h>

// Problem constants (from reference setup_inputs)
#define BB 32
#define CC 64
#define HH 224
#define WW 224
#define HO 112
#define WO 112
#define OPH 17   // ceil((32 + 2 - 1) / 2)
#define OPW 17

// Recompute the 17x17 output patch per (b,c) and scatter into d_out,
// overwriting the stale copied values. Also writes new_loc (as float32,
// since the harness reads the whole flat output buffer as f32).
__global__ void IncMaxPool_patch_kernel(const float* __restrict__ in,
                                        const int* __restrict__ loc,
                                        float* __restrict__ out) {
    const int bc = blockIdx.x;
    const int b = bc / CC;
    const int c = bc % CC;

    // oy = clip(ceil_div(loc0 - 1, 2), 0, Ho - 17) == clip(loc0/2, 0, 95) for loc0 >= 0
    const int l0 = loc[b * 2 + 0];
    const int l1 = loc[b * 2 + 1];
    const int oy = min(max(l0 >> 1, 0), HO - OPH);
    const int ox = min(max(l1 >> 1, 0), WO - OPW);

    const float* __restrict__ ibase = in + (size_t)(b * CC + c) * HH * WW;
    float* __restrict__ obase = out + (size_t)(b * CC + c) * HO * WO;

    for (int idx = threadIdx.x; idx < OPH * OPW; idx += blockDim.x) {
        const int i = idx / OPW;
        const int j = idx - i * OPW;
        const int y = oy + i;
        const int x = ox + j;
        // input window rows: y*2 and y*2+1, cols x*2, x*2+1 (8B aligned: x*2 even)
        const float2 r0 = *(const float2*)(ibase + (size_t)(y * 2) * WW + x * 2);
        const float2 r1 = *(const float2*)(ibase + (size_t)(y * 2 + 1) * WW + x * 2);
        obase[y * WO + x] = fmaxf(fmaxf(r0.x, r0.y), fmaxf(r1.x, r1.y));
    }

    // Tail of d_out: new_loc as float32 values (flat buffer is read as f32)
    if (c == 0 && threadIdx.x == 0) {
        float* locout = out + (size_t)BB * CC * HO * WO;
        locout[b * 2 + 0] = (float)oy;
        locout[b * 2 + 1] = (float)ox;
    }
}

extern "C" void kernel_launch(void* const* d_in, const int* in_sizes, int n_in,
                              void* d_out, int out_size, void* d_ws, size_t ws_size,
                              hipStream_t stream) {
    const float* in_tensor  = (const float*)d_in[0];
    const float* out_tensor = (const float*)d_in[1];
    const int*   loc        = (const int*)d_in[2];
    float* out = (float*)d_out;

    // 1) Bulk copy of stale pooled output (102.8 MB) via DMA — must happen
    //    every call since harness doesn't re-poison between replays.
    const size_t bulk_bytes = (size_t)BB * CC * HO * WO * sizeof(float);
    hipMemcpyAsync(out, out_tensor, bulk_bytes, hipMemcpyDeviceToDevice, stream);

    // 2) Recompute + scatter the dirty 17x17 patches (and the loc tail).
    IncMaxPool_patch_kernel<<<BB * CC, 256, 0, stream>>>(in_tensor, loc, out);
}

// Round 2
// 38.255 us; speedup vs baseline: 1.0700x; 1.0700x over previous
//
#include <hip/hip_runtime.h>

// Problem constants (from reference setup_inputs)
#define BB 32
#define CC 64
#define HH 224
#define WW 224
#define HO 112
#define WO 112
#define OPH 17   // ceil((32 + 2 - 1) / 2)
#define OPW 17

#define IMG_F4   (CC * HO * WO / 4)   // 200704 float4 per image
#define CH_F4    (HO * WO / 4)        // 3136 float4 per channel
#define ROW_F4   (WO / 4)             // 28 float4 per output row
#define TOTAL_F4 (BB * IMG_F4)        // 6422528 float4 total

// Single fused pass: copy stale pooled output, but recompute elements that
// fall inside the per-image dirty 17x17 output window from the input tensor.
// Also writes the new_loc tail (as float32 — harness reads flat buffer as f32).
__global__ __launch_bounds__(256)
void IncMaxPool_fused_kernel(const float* __restrict__ in,
                             const float* __restrict__ prev,
                             const int* __restrict__ loc,
                             float* __restrict__ out) {
    const int tid = blockIdx.x * 256 + threadIdx.x;   // one float4 per thread

    // decompose flat float4 index -> (b, c, y, x4)
    const int b  = tid / IMG_F4;
    const int r0 = tid - b * IMG_F4;
    const int c  = r0 / CH_F4;
    const int r1 = r0 - c * CH_F4;
    const int y  = r1 / ROW_F4;
    const int x4 = (r1 - y * ROW_F4) * 4;

    // per-image patch origin (oy = clip(floor(l0/2), 0, 95), same for ox)
    const int l0 = loc[b * 2 + 0];
    const int l1 = loc[b * 2 + 1];
    const int oy = min(max(l0 >> 1, 0), HO - OPH);
    const int ox = min(max(l1 >> 1, 0), WO - OPW);

    float4 v = ((const float4*)prev)[tid];

    // does this float4 overlap the dirty window?
    if (y >= oy && y < oy + OPH && (x4 + 3) >= ox && x4 <= (ox + OPW - 1)) {
        const float* ib = in + (size_t)(b * CC + c) * (HH * WW) + (size_t)(y * 2) * WW;
        float r[4] = {v.x, v.y, v.z, v.w};
        #pragma unroll
        for (int j = 0; j < 4; ++j) {
            const int x = x4 + j;
            if (x >= ox && x < ox + OPW) {
                const float2 a = *(const float2*)(ib + x * 2);        // row y*2
                const float2 d = *(const float2*)(ib + WW + x * 2);   // row y*2+1
                r[j] = fmaxf(fmaxf(a.x, a.y), fmaxf(d.x, d.y));
            }
        }
        v = make_float4(r[0], r[1], r[2], r[3]);
    }

    ((float4*)out)[tid] = v;

    // new_loc tail: 32 (oy, ox) pairs as floats
    if (tid < BB) {
        const int m0 = loc[tid * 2 + 0];
        const int m1 = loc[tid * 2 + 1];
        float* locout = out + (size_t)BB * CC * HO * WO;
        locout[tid * 2 + 0] = (float)min(max(m0 >> 1, 0), HO - OPH);
        locout[tid * 2 + 1] = (float)min(max(m1 >> 1, 0), WO - OPW);
    }
}

extern "C" void kernel_launch(void* const* d_in, const int* in_sizes, int n_in,
                              void* d_out, int out_size, void* d_ws, size_t ws_size,
                              hipStream_t stream) {
    const float* in_tensor  = (const float*)d_in[0];
    const float* out_tensor = (const float*)d_in[1];
    const int*   loc        = (const int*)d_in[2];
    float* out = (float*)d_out;

    // 6422528 float4 / 256 threads = 25088 blocks, exact
    IncMaxPool_fused_kernel<<<TOTAL_F4 / 256, 256, 0, stream>>>(in_tensor, out_tensor, loc, out);
}